// Round 2
// baseline (151.212 us; speedup 1.0000x reference)
//
#include <hip/hip_runtime.h>

// Problem shape (fixed by reference):
//   feat_s, feat_t : [64, 256, 32, 32] float32, integer values in [0,256)
//   out            : scalar float32
#define NBATCH    64
#define BINS      256
#define PER_BATCH (256 * 32 * 32)   // 262144 elements per batch
#define THREADS   256
#define CHUNKS    16                // blocks per batch-tensor
#define F4_PER_CHUNK (PER_BATCH / 4 / CHUNKS)   // 4096 float4 per block
#define F4_PER_THREAD (F4_PER_CHUNK / THREADS)  // 16 float4 = 64 elems/thread

// ---------------------------------------------------------------------------
// Kernel 1: per-batch histograms.
// R2 change: MAXIMIZE per-wave memory-level parallelism. R1 measured
// VGPR_Count=24 -> the compiler rotated the "8-deep" prefetch through ~3
// registers, so each wave had only ~2-4 loads in flight; with ~50% L3-miss
// (FETCH 65MB of 134MB) at ~900cyc the waves sat in vmcnt stalls (VALUBusy
// 5%, LDS ~15%, HBM 24% - nothing busy). Now: __launch_bounds__(256,4)
// (<=128 VGPR) + load ALL 16 float4 into 64 live VGPRs + sched_barrier(0)
// fence so the scheduler cannot sink loads below the atomics. 16 loads in
// flight per wave, guaranteed.
// LDS scheme unchanged from R1 (it is off the critical path):
//   256 rows (bins) x 16 u32 columns, col = tid&15, one ds_add per element
//   (fire-and-forget, no lgkmcnt stall), counter max 16*64=1024.
// 16 KiB x 4+ blocks/CU; grid 2048 = 2 generations of 4/CU (gen-2 loads
// start as gen-1 retires -> natural cross-generation overlap).
// Each block writes a private 256-bin u16 slab (max/bin 16384 < 2^16).
// Block 0 zeroes kl_batch's completion flag (stream-ordered, re-poison safe).
// ---------------------------------------------------------------------------
__global__ __launch_bounds__(THREADS, 4) void hist_kernel(
    const float* __restrict__ fs, const float* __restrict__ ft,
    unsigned short* __restrict__ phist, unsigned* __restrict__ flag) {
  __shared__ unsigned sh[BINS * 16];  // 16 KiB
  const int tid = threadIdx.x;
  if (blockIdx.x == 0 && tid == 0) *flag = 0u;

  // zero LDS: 4096 words / 256 thr = 16 words = 4 x uint4 per thread
  uint4* shv = (uint4*)sh;
#pragma unroll
  for (int k = 0; k < 4; ++k) shv[k * THREADS + tid] = make_uint4(0, 0, 0, 0);

  const int tb    = blockIdx.x >> 4;   // 0..127 : batch-tensor index
  const int chunk = blockIdx.x & 15;
  const float* src   = (tb < NBATCH) ? fs : ft;
  const int    batch = tb & (NBATCH - 1);
  const float4* p = (const float4*)(src + (size_t)batch * PER_BATCH)
                    + (size_t)chunk * F4_PER_CHUNK;

  // Issue ALL 16 global loads first: 64 data VGPRs live, 16 KB in flight
  // per wave. This is the whole point of R2.
  float4 c[F4_PER_THREAD];
#pragma unroll
  for (int k = 0; k < F4_PER_THREAD; ++k) c[k] = p[k * THREADS + tid];
  __builtin_amdgcn_sched_barrier(0);   // do not sink loads below the atomics

  __syncthreads();   // LDS zeroing visible (placed after load-issue: free)

  const unsigned colb = ((unsigned)tid & 15u) << 2;  // column byte offset

#define PROC1(x) {                                              \
    unsigned b = (unsigned)(x);                                 \
    atomicAdd((unsigned*)((char*)sh + ((b << 6) + colb)), 1u); }
#define PROC4(v) { PROC1(v.x) PROC1(v.y) PROC1(v.z) PROC1(v.w) }

#pragma unroll
  for (int k = 0; k < F4_PER_THREAD; ++k) PROC4(c[k])
  __syncthreads();

  // Flush: thread t owns bin t: sum its 16-column row. Rotation (c+t)&15
  // keeps 2 lanes/bank (bank = 16*(t&1) + col). Max sum 16384 -> u16 slab.
  unsigned cnt = 0;
#pragma unroll
  for (int c = 0; c < 16; ++c)
    cnt += sh[((unsigned)tid << 4) + (((unsigned)c + (unsigned)tid) & 15u)];
  phist[blockIdx.x * BINS + tid] = (unsigned short)cnt;
}

// ---------------------------------------------------------------------------
// Kernel 2: per-batch KL partial, one block per batch (64 blocks x 256 thr).
// Sums the 16 u16 chunk-histograms per tensor inline (coalesced), then fp64
// softmax/KL (result is a ~1e-3 sum of cancelling terms; threshold 1.9e-5).
// finalize is FUSED: each block release-stores its partial and bumps a
// device-scope counter; the last block (agent-scope acquire) reduces the 64
// partials in-wave and writes the scalar output.
// ---------------------------------------------------------------------------
__global__ __launch_bounds__(256) void kl_batch(
    const unsigned short* __restrict__ phist, double* __restrict__ partial,
    unsigned* __restrict__ flag, float* __restrict__ out) {
  __shared__ double reda[4], redb[4];
  __shared__ int amLast;
  const int n = blockIdx.x, tid = threadIdx.x;
  const int w = tid >> 6, lane = tid & 63;

  int hs = 0, ht = 0;
#pragma unroll
  for (int c = 0; c < CHUNKS; ++c) {
    hs += (int)phist[(n * CHUNKS + c) * BINS + tid];
    ht += (int)phist[((NBATCH + n) * CHUNKS + c) * BINS + tid];
  }

  // logits = log(hist + 1e-8) / T, T = 4
  double ls = log((double)hs + 1e-8) * 0.25;
  double lt = log((double)ht + 1e-8) * 0.25;

  double ms = ls, mt = lt;
  for (int off = 32; off; off >>= 1) {
    ms = fmax(ms, __shfl_xor(ms, off));
    mt = fmax(mt, __shfl_xor(mt, off));
  }
  if (lane == 0) { reda[w] = ms; redb[w] = mt; }
  __syncthreads();
  ms = fmax(fmax(reda[0], reda[1]), fmax(reda[2], reda[3]));
  mt = fmax(fmax(redb[0], redb[1]), fmax(redb[2], redb[3]));
  __syncthreads();

  double ss = exp(ls - ms), st = exp(lt - mt);
  for (int off = 32; off; off >>= 1) {
    ss += __shfl_xor(ss, off);
    st += __shfl_xor(st, off);
  }
  if (lane == 0) { reda[w] = ss; redb[w] = st; }
  __syncthreads();
  ss = reda[0] + reda[1] + reda[2] + reda[3];
  st = redb[0] + redb[1] + redb[2] + redb[3];
  const double lse_s = ms + log(ss);
  const double lse_t = mt + log(st);

  const double lpt = lt - lse_t;
  const double lps = ls - lse_s;
  double term = exp(lpt) * (lpt - lps);
  for (int off = 32; off; off >>= 1) term += __shfl_xor(term, off);
  __syncthreads();                 // protect reda reuse
  if (lane == 0) reda[w] = term;
  __syncthreads();

  if (tid == 0) {
    double bsum = reda[0] + reda[1] + reda[2] + reda[3];
    __hip_atomic_store(&partial[n], bsum, __ATOMIC_RELEASE,
                       __HIP_MEMORY_SCOPE_AGENT);
    unsigned prev = __hip_atomic_fetch_add(flag, 1u, __ATOMIC_ACQ_REL,
                                           __HIP_MEMORY_SCOPE_AGENT);
    amLast = (prev == (unsigned)(NBATCH - 1)) ? 1 : 0;
  }
  __syncthreads();

  if (amLast && tid < 64) {
    double v = __hip_atomic_load(&partial[tid], __ATOMIC_ACQUIRE,
                                 __HIP_MEMORY_SCOPE_AGENT);
    for (int off = 32; off; off >>= 1) v += __shfl_xor(v, off);
    if (tid == 0) out[0] = (float)(v * 0.25);   // * T^2 / N = 16/64
  }
}

// ---------------------------------------------------------------------------
extern "C" void kernel_launch(void* const* d_in, const int* in_sizes, int n_in,
                              void* d_out, int out_size, void* d_ws, size_t ws_size,
                              hipStream_t stream) {
  const float* fs = (const float*)d_in[0];
  const float* ft = (const float*)d_in[1];
  // ws: 2048 block-private 256-bin u16 slabs (1 MiB) + 64 doubles + flag.
  unsigned short* phist = (unsigned short*)d_ws;
  double* partial = (double*)((char*)d_ws +
                              (size_t)128 * CHUNKS * BINS * sizeof(unsigned short));
  unsigned* flag = (unsigned*)((char*)partial + NBATCH * sizeof(double));

  hist_kernel<<<dim3(128 * CHUNKS), dim3(THREADS), 0, stream>>>(fs, ft, phist, flag);
  kl_batch<<<dim3(NBATCH), dim3(256), 0, stream>>>(phist, partial, flag, (float*)d_out);
}

// Round 3
// 150.366 us; speedup vs baseline: 1.0056x; 1.0056x over previous
//
#include <hip/hip_runtime.h>

// Problem shape (fixed by reference):
//   feat_s, feat_t : [64, 256, 32, 32] float32, integer values in [0,256)
//   out            : scalar float32
#define NBATCH    64
#define BINS      256
#define PER_BATCH (256 * 32 * 32)   // 262144 elements per batch
#define THREADS   256
#define CHUNKS    16                // blocks per batch-tensor
#define F4_PER_CHUNK (PER_BATCH / 4 / CHUNKS)   // 4096 float4 per block
#define F4_PER_THREAD (F4_PER_CHUNK / THREADS)  // 16 float4 = 64 elems/thread

typedef float f32x4 __attribute__((ext_vector_type(4)));

// ---------------------------------------------------------------------------
// Kernel 1: per-batch histograms.
// R3 change: FORCE 16-deep memory-level parallelism with inline asm.
// History: R1 (VGPR=24) and R2 (VGPR=36, sched_barrier) both show the
// compiler collapsing the 16-float4 load batch into 2-3 rotated dest tuples
// with WAW waitcnts between loads -> ~3 KB in flight per CU -> 1.5 TB/s
// HBM (Little's law at ~600cyc latency), all pipes idle (VALU 5%, LDS
// conflicts ~5k cyc/CU). Fix: 16 x asm global_load_dwordx4 with 16 DISTINCT
// live f32x4 outputs (RA cannot collapse asm results), consumed under
// progressive `s_waitcnt vmcnt(15-k)` that is tied "+v" to the consumed
// value (data-dependence ordering: nothing can read cc[k] before its wait;
// no sched_barrier needed). LDS-zero + barrier precede load issue so no
// compiler-emitted barrier drain sits between issue and consume.
// 16 KB in flight/wave x 16+ waves/CU >> ~6 KB/CU needed for 6.3 TB/s.
// LDS scheme unchanged (off critical path): 256 bins x 16 u32 cols,
// col = tid&15, bank = col + 16*(bin&1) -> avg 2 lanes/bank; one
// fire-and-forget ds_add per element; counter max 16*64 = 1024.
// This round is also the discriminator: if hist stays ~45us WITH
// VGPR~90 (loads provably in flight), the wall is the LDS-atomic path,
// not MLP -> restructure histogram next.
// ---------------------------------------------------------------------------
__global__ __launch_bounds__(THREADS, 4) void hist_kernel(
    const float* __restrict__ fs, const float* __restrict__ ft,
    unsigned short* __restrict__ phist, unsigned* __restrict__ flag) {
  __shared__ unsigned sh[BINS * 16];  // 16 KiB
  const int tid = threadIdx.x;

  // zero LDS first, barrier BEFORE load issue (keeps issue->consume
  // window free of vmcnt-draining barriers).
  uint4* shv = (uint4*)sh;
#pragma unroll
  for (int k = 0; k < 4; ++k) shv[k * THREADS + tid] = make_uint4(0, 0, 0, 0);
  __syncthreads();

  const int tb    = blockIdx.x >> 4;   // 0..127 : batch-tensor index
  const int chunk = blockIdx.x & 15;
  const float* src   = (tb < NBATCH) ? fs : ft;
  const int    batch = tb & (NBATCH - 1);
  const float4* p = (const float4*)(src + (size_t)batch * PER_BATCH)
                    + (size_t)chunk * F4_PER_CHUNK;

  // Issue ALL 16 loads back-to-back: uniform SGPR base + per-lane voffset.
  // Asm outputs are 16 distinct live quads -> 64 data VGPRs, un-collapsible.
  const unsigned long long base = (unsigned long long)p;
  const unsigned voff0 = (unsigned)tid * 16u;
  f32x4 cc[F4_PER_THREAD];
#pragma unroll
  for (int k = 0; k < F4_PER_THREAD; ++k) {
    asm volatile("global_load_dwordx4 %0, %1, %2"
                 : "=v"(cc[k])
                 : "v"(voff0 + (unsigned)k * 4096u), "s"(base));
  }

  const unsigned colb = ((unsigned)tid & 15u) << 2;  // column byte offset

#define PROC1(x) {                                              \
    unsigned b = (unsigned)(x);                                 \
    atomicAdd((unsigned*)((char*)sh + ((b << 6) + colb)), 1u); }
#define PROC4(v) { PROC1(v[0]) PROC1(v[1]) PROC1(v[2]) PROC1(v[3]) }

  // Progressive retire: c[k] is safe once <=15-k of this wave's vmem ops
  // are outstanding (in-order retirement). The "+v" tie makes every use of
  // cc[k] data-dependent on the waitcnt -> compiler cannot hoist a read of
  // the load dest above the wait (rule #18 equivalent, dependency-based).
#pragma unroll
  for (int k = 0; k < F4_PER_THREAD; ++k) {
    asm volatile("s_waitcnt vmcnt(%1)" : "+v"(cc[k]) : "n"(F4_PER_THREAD - 1 - k));
    PROC4(cc[k])
  }
  __syncthreads();

  // Flush: thread t owns bin t: sum its 16-column row. Rotation (c+t)&15
  // keeps 2 lanes/bank. Max sum 16384 -> u16 slab.
  unsigned cnt = 0;
#pragma unroll
  for (int c = 0; c < 16; ++c)
    cnt += sh[((unsigned)tid << 4) + (((unsigned)c + (unsigned)tid) & 15u)];
  phist[blockIdx.x * BINS + tid] = (unsigned short)cnt;

  // Zero kl_batch's completion flag (stream-ordered before kl_batch;
  // re-zeroed every iteration => re-poison safe). Placed at kernel end so
  // the store does not perturb the progressive vmcnt arithmetic above.
  if (blockIdx.x == 0 && tid == 0) *flag = 0u;
}

// ---------------------------------------------------------------------------
// Kernel 2: per-batch KL partial, one block per batch (64 blocks x 256 thr).
// Sums the 16 u16 chunk-histograms per tensor inline (coalesced), then fp64
// softmax/KL (result is a ~1e-3 sum of cancelling terms; threshold 1.9e-5).
// finalize FUSED: each block release-stores its partial and bumps a
// device-scope counter; the last block (agent-scope acquire) reduces the 64
// partials in-wave and writes the scalar output.
// ---------------------------------------------------------------------------
__global__ __launch_bounds__(256) void kl_batch(
    const unsigned short* __restrict__ phist, double* __restrict__ partial,
    unsigned* __restrict__ flag, float* __restrict__ out) {
  __shared__ double reda[4], redb[4];
  __shared__ int amLast;
  const int n = blockIdx.x, tid = threadIdx.x;
  const int w = tid >> 6, lane = tid & 63;

  int hs = 0, ht = 0;
#pragma unroll
  for (int c = 0; c < CHUNKS; ++c) {
    hs += (int)phist[(n * CHUNKS + c) * BINS + tid];
    ht += (int)phist[((NBATCH + n) * CHUNKS + c) * BINS + tid];
  }

  // logits = log(hist + 1e-8) / T, T = 4
  double ls = log((double)hs + 1e-8) * 0.25;
  double lt = log((double)ht + 1e-8) * 0.25;

  double ms = ls, mt = lt;
  for (int off = 32; off; off >>= 1) {
    ms = fmax(ms, __shfl_xor(ms, off));
    mt = fmax(mt, __shfl_xor(mt, off));
  }
  if (lane == 0) { reda[w] = ms; redb[w] = mt; }
  __syncthreads();
  ms = fmax(fmax(reda[0], reda[1]), fmax(reda[2], reda[3]));
  mt = fmax(fmax(redb[0], redb[1]), fmax(redb[2], redb[3]));
  __syncthreads();

  double ss = exp(ls - ms), st = exp(lt - mt);
  for (int off = 32; off; off >>= 1) {
    ss += __shfl_xor(ss, off);
    st += __shfl_xor(st, off);
  }
  if (lane == 0) { reda[w] = ss; redb[w] = st; }
  __syncthreads();
  ss = reda[0] + reda[1] + reda[2] + reda[3];
  st = redb[0] + redb[1] + redb[2] + redb[3];
  const double lse_s = ms + log(ss);
  const double lse_t = mt + log(st);

  const double lpt = lt - lse_t;
  const double lps = ls - lse_s;
  double term = exp(lpt) * (lpt - lps);
  for (int off = 32; off; off >>= 1) term += __shfl_xor(term, off);
  __syncthreads();                 // protect reda reuse
  if (lane == 0) reda[w] = term;
  __syncthreads();

  if (tid == 0) {
    double bsum = reda[0] + reda[1] + reda[2] + reda[3];
    __hip_atomic_store(&partial[n], bsum, __ATOMIC_RELEASE,
                       __HIP_MEMORY_SCOPE_AGENT);
    unsigned prev = __hip_atomic_fetch_add(flag, 1u, __ATOMIC_ACQ_REL,
                                           __HIP_MEMORY_SCOPE_AGENT);
    amLast = (prev == (unsigned)(NBATCH - 1)) ? 1 : 0;
  }
  __syncthreads();

  if (amLast && tid < 64) {
    double v = __hip_atomic_load(&partial[tid], __ATOMIC_ACQUIRE,
                                 __HIP_MEMORY_SCOPE_AGENT);
    for (int off = 32; off; off >>= 1) v += __shfl_xor(v, off);
    if (tid == 0) out[0] = (float)(v * 0.25);   // * T^2 / N = 16/64
  }
}

// ---------------------------------------------------------------------------
extern "C" void kernel_launch(void* const* d_in, const int* in_sizes, int n_in,
                              void* d_out, int out_size, void* d_ws, size_t ws_size,
                              hipStream_t stream) {
  const float* fs = (const float*)d_in[0];
  const float* ft = (const float*)d_in[1];
  // ws: 2048 block-private 256-bin u16 slabs (1 MiB) + 64 doubles + flag.
  unsigned short* phist = (unsigned short*)d_ws;
  double* partial = (double*)((char*)d_ws +
                              (size_t)128 * CHUNKS * BINS * sizeof(unsigned short));
  unsigned* flag = (unsigned*)((char*)partial + NBATCH * sizeof(double));

  hist_kernel<<<dim3(128 * CHUNKS), dim3(THREADS), 0, stream>>>(fs, ft, phist, flag);
  kl_batch<<<dim3(NBATCH), dim3(256), 0, stream>>>(phist, partial, flag, (float*)d_out);
}

// Round 5
// 149.872 us; speedup vs baseline: 1.0089x; 1.0033x over previous
//
#include <hip/hip_runtime.h>

// Problem shape (fixed by reference):
//   feat_s, feat_t : [64, 256, 32, 32] float32, integer values in [0,256)
//   out            : scalar float32
#define NBATCH    64
#define BINS      256
#define PER_BATCH (256 * 32 * 32)   // 262144 elements per batch
#define THREADS   256
#define CHUNKS    4                 // blocks per batch-tensor (R4: was 16)
#define ELEM_PER_CHUNK (PER_BATCH / CHUNKS)      // 65536 elements per block
#define F4_PER_THREAD  (ELEM_PER_CHUNK / 4 / THREADS)  // 64 float4 per thread

typedef float f32x4 __attribute__((ext_vector_type(4)));

// ---------------------------------------------------------------------------
// Kernel 1: per-batch histograms.
// R5 = R4 design with the macro-capture bug fixed (PROC1's local was named
// `b`, shadowing the register array `b` passed to CONS8 -> "subscripted
// value is not an array"). Local renamed bin_, buffers renamed ra/rb.
//
// R4 rationale (unchanged): R1/R2/R3 (three structures, 2048 blocks each)
// all ran 45-48us with NOTHING busy (VALU 5%, LDS ~13%, HBM 18%) and R3's
// VGPR=36 proved the 16-deep load batch never materialized. Surviving
// theories: (a) per-block fixed/dispatch overhead at 2048 WGs; (b) per-wave
// MLP stuck ~2. This kernel attacks both: grid 512 (2 blocks/CU, ONE
// generation), each block does 4x the work (65536 elems = 256KB), loads go
// through a rolling 8+8 double buffer of inline-asm global_load_dwordx4
// with s_waitcnt vmcnt(8) between halves (16KB in flight/wave steady-state,
// never drained to 0 mid-loop). 8 waves/CU x 16KB >> Little's-law needs.
// OccupancyPercent will read ~25% - by design, not a regression.
// LDS scheme unchanged (measured off critical path): 256 bins x 16 u32
// cols, col = tid&15, one fire-and-forget ds_add per element; counter max
// 16 thr x 256 elem = 4096.
// Slabs are u32: per-block bin count can reach 65536 (adversarial data),
// which would overflow u16.
// ---------------------------------------------------------------------------
__global__ __launch_bounds__(THREADS, 2) void hist_kernel(
    const float* __restrict__ fs, const float* __restrict__ ft,
    unsigned* __restrict__ phist, unsigned* __restrict__ flag) {
  __shared__ unsigned sh[BINS * 16];  // 16 KiB
  const int tid = threadIdx.x;

  // zero LDS, barrier BEFORE load issue (no barrier drain inside the
  // issue->consume window).
  uint4* shv = (uint4*)sh;
#pragma unroll
  for (int k = 0; k < 4; ++k) shv[k * THREADS + tid] = make_uint4(0, 0, 0, 0);
  __syncthreads();

  const int tb    = blockIdx.x >> 2;   // 0..127 : batch-tensor index
  const int chunk = blockIdx.x & 3;
  const float* src   = (tb < NBATCH) ? fs : ft;
  const int    batch = tb & (NBATCH - 1);
  const float* pf = src + (size_t)batch * PER_BATCH + (size_t)chunk * ELEM_PER_CHUNK;

  const unsigned long long base = (unsigned long long)pf;
  const unsigned voff0 = (unsigned)tid * 16u;   // float4 lane byte offset

  // ---- forced-MLP load machinery -----------------------------------------
  // j-th float4 of this thread lives at byte offset voff0 + j*4096.
  // ISSUE8: 8 back-to-back asm loads, 8 DISTINCT live f32x4 dests (RA
  // cannot collapse asm results). WAITBUF ties the waited buffer's
  // registers ("+v") so every consume is data-dependent on its waitcnt -
  // no hoisting of a dest read above the wait; volatile pins issue order.
#define ISSUE8(buf, j0)                                                      \
  {                                                                          \
    _Pragma("unroll")                                                        \
    for (int s = 0; s < 8; ++s)                                              \
      asm volatile("global_load_dwordx4 %0, %1, %2"                          \
                   : "=v"(buf[s])                                            \
                   : "v"(voff0 + (unsigned)(j0 + s) * 4096u), "s"(base));    \
  }
#define WAITBUF(buf, n)                                                      \
  asm volatile("s_waitcnt vmcnt(" #n ")"                                     \
               : "+v"(buf[0]), "+v"(buf[1]), "+v"(buf[2]), "+v"(buf[3]),     \
                 "+v"(buf[4]), "+v"(buf[5]), "+v"(buf[6]), "+v"(buf[7]));

  const unsigned colb = ((unsigned)tid & 15u) << 2;  // column byte offset
#define PROC1(x) {                                                \
    unsigned bin_ = (unsigned)(x);                                \
    atomicAdd((unsigned*)((char*)sh + ((bin_ << 6) + colb)), 1u); }
#define CONS8(buf)                                                           \
  {                                                                          \
    _Pragma("unroll")                                                        \
    for (int s = 0; s < 8; ++s) {                                            \
      PROC1(buf[s][0]) PROC1(buf[s][1]) PROC1(buf[s][2]) PROC1(buf[s][3])    \
    }                                                                        \
  }

  f32x4 ra[8], rb[8];
  ISSUE8(ra, 0) ISSUE8(rb, 8)                  // 16 in flight
  // rounds: consume 8, refill 8 -> outstanding oscillates 16 -> 8 -> 16
  WAITBUF(ra, 8) CONS8(ra) ISSUE8(ra, 16)
  WAITBUF(rb, 8) CONS8(rb) ISSUE8(rb, 24)
  WAITBUF(ra, 8) CONS8(ra) ISSUE8(ra, 32)
  WAITBUF(rb, 8) CONS8(rb) ISSUE8(rb, 40)
  WAITBUF(ra, 8) CONS8(ra) ISSUE8(ra, 48)
  WAITBUF(rb, 8) CONS8(rb) ISSUE8(rb, 56)
  // final round: no refill; ra ready at vmcnt(8), rb needs full drain
  WAITBUF(ra, 8) CONS8(ra)
  WAITBUF(rb, 0) CONS8(rb)
  __syncthreads();

  // Flush: thread t owns bin t: sum its 16-column row. Rotation (c+t)&15
  // keeps 2 lanes/bank. Max sum 65536 -> u32 slab.
  unsigned cnt = 0;
#pragma unroll
  for (int c = 0; c < 16; ++c)
    cnt += sh[((unsigned)tid << 4) + (((unsigned)c + (unsigned)tid) & 15u)];
  phist[blockIdx.x * BINS + tid] = cnt;

  // Zero kl_batch's completion flag (stream-ordered before kl_batch; re-done
  // every iteration => re-poison safe).
  if (blockIdx.x == 0 && tid == 0) *flag = 0u;
}

// ---------------------------------------------------------------------------
// Kernel 2: per-batch KL partial, one block per batch (64 blocks x 256 thr).
// Sums the 4 u32 chunk-histograms per tensor inline (coalesced), then fp64
// softmax/KL (result is a ~1e-3 sum of cancelling terms; threshold 1.9e-5).
// finalize FUSED: each block release-stores its partial and bumps a
// device-scope counter; the last block (agent-scope acquire) reduces the 64
// partials in-wave and writes the scalar output.
// ---------------------------------------------------------------------------
__global__ __launch_bounds__(256) void kl_batch(
    const unsigned* __restrict__ phist, double* __restrict__ partial,
    unsigned* __restrict__ flag, float* __restrict__ out) {
  __shared__ double reda[4], redb[4];
  __shared__ int amLast;
  const int n = blockIdx.x, tid = threadIdx.x;
  const int w = tid >> 6, lane = tid & 63;

  unsigned hs = 0, ht = 0;
#pragma unroll
  for (int c = 0; c < CHUNKS; ++c) {
    hs += phist[(n * CHUNKS + c) * BINS + tid];
    ht += phist[((NBATCH + n) * CHUNKS + c) * BINS + tid];
  }

  // logits = log(hist + 1e-8) / T, T = 4
  double ls = log((double)hs + 1e-8) * 0.25;
  double lt = log((double)ht + 1e-8) * 0.25;

  double ms = ls, mt = lt;
  for (int off = 32; off; off >>= 1) {
    ms = fmax(ms, __shfl_xor(ms, off));
    mt = fmax(mt, __shfl_xor(mt, off));
  }
  if (lane == 0) { reda[w] = ms; redb[w] = mt; }
  __syncthreads();
  ms = fmax(fmax(reda[0], reda[1]), fmax(reda[2], reda[3]));
  mt = fmax(fmax(redb[0], redb[1]), fmax(redb[2], redb[3]));
  __syncthreads();

  double ss = exp(ls - ms), st = exp(lt - mt);
  for (int off = 32; off; off >>= 1) {
    ss += __shfl_xor(ss, off);
    st += __shfl_xor(st, off);
  }
  if (lane == 0) { reda[w] = ss; redb[w] = st; }
  __syncthreads();
  ss = reda[0] + reda[1] + reda[2] + reda[3];
  st = redb[0] + redb[1] + redb[2] + redb[3];
  const double lse_s = ms + log(ss);
  const double lse_t = mt + log(st);

  const double lpt = lt - lse_t;
  const double lps = ls - lse_s;
  double term = exp(lpt) * (lpt - lps);
  for (int off = 32; off; off >>= 1) term += __shfl_xor(term, off);
  __syncthreads();                 // protect reda reuse
  if (lane == 0) reda[w] = term;
  __syncthreads();

  if (tid == 0) {
    double bsum = reda[0] + reda[1] + reda[2] + reda[3];
    __hip_atomic_store(&partial[n], bsum, __ATOMIC_RELEASE,
                       __HIP_MEMORY_SCOPE_AGENT);
    unsigned prev = __hip_atomic_fetch_add(flag, 1u, __ATOMIC_ACQ_REL,
                                           __HIP_MEMORY_SCOPE_AGENT);
    amLast = (prev == (unsigned)(NBATCH - 1)) ? 1 : 0;
  }
  __syncthreads();

  if (amLast && tid < 64) {
    double v = __hip_atomic_load(&partial[tid], __ATOMIC_ACQUIRE,
                                 __HIP_MEMORY_SCOPE_AGENT);
    for (int off = 32; off; off >>= 1) v += __shfl_xor(v, off);
    if (tid == 0) out[0] = (float)(v * 0.25);   // * T^2 / N = 16/64
  }
}

// ---------------------------------------------------------------------------
extern "C" void kernel_launch(void* const* d_in, const int* in_sizes, int n_in,
                              void* d_out, int out_size, void* d_ws, size_t ws_size,
                              hipStream_t stream) {
  const float* fs = (const float*)d_in[0];
  const float* ft = (const float*)d_in[1];
  // ws: 512 block-private 256-bin u32 slabs (512 KiB) + 64 doubles + flag.
  unsigned* phist = (unsigned*)d_ws;
  double* partial = (double*)((char*)d_ws +
                              (size_t)128 * CHUNKS * BINS * sizeof(unsigned));
  unsigned* flag = (unsigned*)((char*)partial + NBATCH * sizeof(double));

  hist_kernel<<<dim3(128 * CHUNKS), dim3(THREADS), 0, stream>>>(fs, ft, phist, flag);
  kl_batch<<<dim3(NBATCH), dim3(256), 0, stream>>>(phist, partial, flag, (float*)d_out);
}